// Round 7
// baseline (245.225 us; speedup 1.0000x reference)
//
#include <hip/hip_runtime.h>
#include <hip/hip_bf16.h>
#include <math.h>

#define DIM 768
#define NHEADS 16
#define HD 48
#define NTOK 1568
#define BATCH 4
#define ROWS (BATCH * NTOK)     // 6272
#define QKV_COLS (3 * DIM)      // 2304

typedef __attribute__((ext_vector_type(8))) short bf16x8;
typedef __attribute__((ext_vector_type(4))) float f32x4;

__device__ inline float b2f(ushort u) {
    union { float f; unsigned u; } v; v.u = ((unsigned)u) << 16; return v.f;
}
__device__ inline ushort f2b(float f) {
    union { float f; unsigned u; } v; v.f = f;
    unsigned r = v.u + 0x7fff + ((v.u >> 16) & 1);   // round-to-nearest-even
    return (ushort)(r >> 16);
}

// ---------------- cast fp32 -> bf16 (vectorized) -----------------------------
__global__ void cast_f32_bf16(const float* __restrict__ in, ushort* __restrict__ out, int n4) {
    int i = blockIdx.x * blockDim.x + threadIdx.x;
    if (i >= n4) return;
    float4 v = ((const float4*)in)[i];
    ushort4 o;
    o.x = f2b(v.x); o.y = f2b(v.y); o.z = f2b(v.z); o.w = f2b(v.w);
    ((ushort4*)out)[i] = o;
}

// ---------------- transpose-cast: in[R][C] f32 -> out[C][R] bf16 -------------
__global__ void transpose_cast(const float* __restrict__ in, ushort* __restrict__ out,
                               int R, int C) {
    __shared__ ushort tile[32][33];
    int tx = threadIdx.x, ty = threadIdx.y;
    int c0 = blockIdx.x * 32, r0 = blockIdx.y * 32;
#pragma unroll
    for (int k = 0; k < 4; ++k)
        tile[ty + 8 * k][tx] = f2b(in[(size_t)(r0 + ty + 8 * k) * C + c0 + tx]);
    __syncthreads();
#pragma unroll
    for (int k = 0; k < 4; ++k)
        out[(size_t)(c0 + ty + 8 * k) * R + r0 + tx] = tile[tx][ty + 8 * k];
}

// ------- split-transpose W_proj [768][768] f32 -> out[768][2304] = [wh|wh|wl]
__global__ void split_transpose_wp(const float* __restrict__ in, ushort* __restrict__ out) {
    __shared__ float tile[32][33];
    int tx = threadIdx.x, ty = threadIdx.y;
    int c0 = blockIdx.x * 32, r0 = blockIdx.y * 32;   // r = k, c = n
#pragma unroll
    for (int k = 0; k < 4; ++k)
        tile[ty + 8 * k][tx] = in[(size_t)(r0 + ty + 8 * k) * DIM + c0 + tx];
    __syncthreads();
#pragma unroll
    for (int k = 0; k < 4; ++k) {
        float w = tile[tx][ty + 8 * k];
        ushort hi = f2b(w);
        ushort lo = f2b(w - b2f(hi));
        size_t base = (size_t)(c0 + ty + 8 * k) * QKV_COLS + r0 + tx;
        out[base] = hi; out[base + DIM] = hi; out[base + 2 * DIM] = lo;
    }
}

// ------- transpose V slice of qkv: vt[b][c][n] = qkv[b][n][1536+c], c in [0,768)
__global__ void transpose_v(const ushort* __restrict__ qkv, ushort* __restrict__ vt) {
    __shared__ ushort tile[32][33];
    int tx = threadIdx.x, ty = threadIdx.y;   // 32x8
    int c0 = blockIdx.x * 32, n0 = blockIdx.y * 32, b = blockIdx.z;
    const ushort* src = qkv + (size_t)b * NTOK * QKV_COLS + 2 * DIM;
#pragma unroll
    for (int k = 0; k < 4; ++k)
        tile[ty + 8 * k][tx] = src[(size_t)(n0 + ty + 8 * k) * QKV_COLS + c0 + tx];
    __syncthreads();
    ushort* dst = vt + (size_t)b * DIM * NTOK;
#pragma unroll
    for (int k = 0; k < 4; ++k)
        dst[(size_t)(c0 + ty + 8 * k) * NTOK + n0 + tx] = tile[tx][ty + 8 * k];
}

// ---------------- bf16 MFMA GEMM: C[M][N] = A[M][K] * Bt[N][K]^T -------------
#define GBM 128
#define GBN 128
#define GBK 64
#define LDP 72   // LDS pitch (bf16 elems)

__global__ __launch_bounds__(256) void gemm_bf16(
    const ushort* __restrict__ A, const ushort* __restrict__ Bt,
    float* __restrict__ Cf, ushort* __restrict__ Cb,
    const float* __restrict__ bias, int M, int N, int K) {
    __shared__ ushort sA[GBM * LDP];
    __shared__ ushort sB[GBN * LDP];
    const int tid = threadIdx.x;
    const int wid = tid >> 6, lane = tid & 63;
    const int wm = wid >> 1, wn = wid & 1;          // 2x2 wave grid, 64x64 per wave
    const int m0 = blockIdx.y * GBM, n0 = blockIdx.x * GBN;
    const int lr = lane & 15, lk = (lane >> 4) << 3;

    f32x4 acc[4][4] = {};
    for (int k0 = 0; k0 < K; k0 += GBK) {
        __syncthreads();
#pragma unroll
        for (int i = 0; i < 4; ++i) {
            int ci = tid + 256 * i;                  // 1024 chunks of 16B
            int row = ci >> 3, ch = ci & 7;
            *(bf16x8*)&sA[row * LDP + ch * 8] =
                *(const bf16x8*)&A[(size_t)(m0 + row) * K + k0 + ch * 8];
            *(bf16x8*)&sB[row * LDP + ch * 8] =
                *(const bf16x8*)&Bt[(size_t)(n0 + row) * K + k0 + ch * 8];
        }
        __syncthreads();
#pragma unroll
        for (int k2 = 0; k2 < GBK; k2 += 32) {
            bf16x8 af[4], bg[4];
#pragma unroll
            for (int f = 0; f < 4; ++f) {
                af[f] = *(const bf16x8*)&sA[(wm * 64 + f * 16 + lr) * LDP + k2 + lk];
                bg[f] = *(const bf16x8*)&sB[(wn * 64 + f * 16 + lr) * LDP + k2 + lk];
            }
#pragma unroll
            for (int mi = 0; mi < 4; ++mi)
#pragma unroll
                for (int ni = 0; ni < 4; ++ni)
                    acc[mi][ni] = __builtin_amdgcn_mfma_f32_16x16x32_bf16(
                        af[mi], bg[ni], acc[mi][ni], 0, 0, 0);
        }
    }
    const int cr = (lane >> 4) * 4;
#pragma unroll
    for (int mi = 0; mi < 4; ++mi)
#pragma unroll
        for (int ni = 0; ni < 4; ++ni) {
            int col = n0 + wn * 64 + ni * 16 + lr;
#pragma unroll
            for (int j = 0; j < 4; ++j) {
                int row = m0 + wm * 64 + mi * 16 + cr + j;
                float v = acc[mi][ni][j];
                if (Cf) {
                    if (bias) v += bias[col];
                    Cf[(size_t)row * N + col] = v;
                } else {
                    Cb[(size_t)row * N + col] = f2b(v);
                }
            }
        }
}

// ---------------- RoPE 3D in-place on bf16 qkv (q,k halves) ------------------
__global__ void rope_bf16(ushort* __restrict__ qkv, const int* __restrict__ pos) {
    int idx = blockIdx.x * blockDim.x + threadIdx.x;
    const int total = BATCH * NTOK * NHEADS * 3 * 8;   // 2408448
    if (idx >= total) return;
    int j = idx & 7; int t = idx >> 3;
    int axis = t % 3; t /= 3;
    int h = t & 15; t >>= 4;
    int n = t % NTOK; int b = t / NTOK;

    float p = (float)pos[n * 3 + axis];
    float freq = __powf(10000.0f, -(float)j * 0.125f);
    float ang = p * freq;
    float s, c; __sincosf(ang, &s, &c);

    size_t base = ((size_t)b * NTOK + n) * QKV_COLS + h * HD + axis * 16 + j;
    float q1 = b2f(qkv[base]), q2 = b2f(qkv[base + 8]);
    qkv[base]     = f2b(q1 * c - q2 * s);
    qkv[base + 8] = f2b(q2 * c + q1 * s);
    size_t kb = base + DIM;
    float k1 = b2f(qkv[kb]), k2 = b2f(qkv[kb + 8]);
    qkv[kb]     = f2b(k1 * c - k2 * s);
    qkv[kb + 8] = f2b(k2 * c + k1 * s);
}

// ---------------- MFMA flash attention (swapped-operand, fixed-offset SM) ----
// Grid: (13 q-tiles, 64 b*h). Block: 256 thr = 4 waves; wave owns 32 q-rows.
// S^T = mfma(K,Q): lane holds q=lane&15 fixed, keys 4g+j contiguous ->
// cvt_pk + b64 P-stores into row-major sP[q][key]. PV swapped too:
// o^T = mfma(V^T, P): lane holds q=lane&15, d=16nf+4g+j -> ushort4 C-stores.
// KVB=64; 1568 = 24*64+32 -> tail masks local keys>=32 (f>=2) to zero.
#define QBLK 128
#define KVB 64
#define QP 72     // sQ/sK pitch (bf16)
#define VP 72     // sVT pitch
#define PP 72     // sP pitch (q-stride 144B: 16B-aligned, conflict-free)

__global__ __launch_bounds__(256) void attn_mfma(const ushort* __restrict__ qkv,
                                                 const ushort* __restrict__ vt,
                                                 ushort* __restrict__ asplit) {
    __shared__ ushort sQ[QBLK * QP];
    __shared__ ushort sK[KVB * QP];
    __shared__ ushort sVT[HD * VP];
    __shared__ ushort sP[4][32 * PP];
    const int tid = threadIdx.x, w = tid >> 6, lane = tid & 63;
    const int b = blockIdx.y >> 4, h = blockIdx.y & 15;
    const int q0 = blockIdx.x * QBLK;
    const size_t bbase = (size_t)b * NTOK * QKV_COLS;
    const size_t vbase = ((size_t)b * DIM + h * HD) * NTOK;
    const int lr = lane & 15, g = lane >> 4, lk = g << 3;
    // 1/sqrt(48) * log2(e): MFMA output lands directly in exp2 domain
    const float qs = 0.14433756729740643f * 1.4426950408889634f;
    const float M2 = 32.0f;   // fixed exp2-domain offset

    // stage Q (128 rows x 64 cols), pre-scaled; zero-pad cols 48..63 (REQUIRED:
    // K cols 48..63 are unmasked garbage, Q zeros null them in the dot product)
#pragma unroll
    for (int i = 0; i < 4; ++i) {
        int ci = tid + 256 * i;
        int row = ci >> 3, ch = ci & 7;
        int gr = q0 + row; if (gr >= NTOK) gr = NTOK - 1;
        bf16x8 v = {};
        if (ch < 6) {
            bf16x8 r = *(const bf16x8*)&qkv[bbase + (size_t)gr * QKV_COLS + h * HD + ch * 8];
#pragma unroll
            for (int e = 0; e < 8; ++e) v[e] = (short)f2b(b2f((ushort)r[e]) * qs);
        }
        *(bf16x8*)&sQ[row * QP + ch * 8] = v;
    }
    __syncthreads();
    bf16x8 aq[2][2];
#pragma unroll
    for (int rb = 0; rb < 2; ++rb)
#pragma unroll
        for (int ks = 0; ks < 2; ++ks)
            aq[rb][ks] = *(const bf16x8*)&sQ[(w * 32 + rb * 16 + lr) * QP + ks * 32 + lk];

    float l[2] = {0.f, 0.f};
    f32x4 o[2][3] = {};

    for (int kv0 = 0; kv0 < NTOK; kv0 += KVB) {
        const bool tail = (kv0 + KVB > NTOK);   // wave-uniform
        __syncthreads();
        // stage K: 64 rows x 8 chunks = 512 b128 writes (cols 48..63 = garbage, ok)
#pragma unroll
        for (int i = 0; i < 2; ++i) {
            int ci = tid + 256 * i;
            int row = ci >> 3, ch = ci & 7;
            *(bf16x8*)&sK[row * QP + ch * 8] =
                *(const bf16x8*)&qkv[bbase + (size_t)(kv0 + row) * QKV_COLS + DIM + h * HD + ch * 8];
        }
        // stage V^T: 48 d-rows x 8 chunks = 384 (zero chunks past NTOK: no NaN*0)
        {
            int row = tid >> 3, ch = tid & 7;
            bf16x8 v = {};
            if (kv0 + ch * 8 < NTOK)
                v = *(const bf16x8*)&vt[vbase + (size_t)row * NTOK + kv0 + ch * 8];
            *(bf16x8*)&sVT[row * VP + ch * 8] = v;
            if (tid < 128) {
                int ci = tid + 256;
                int row2 = ci >> 3, ch2 = ci & 7;
                bf16x8 v2 = {};
                if (kv0 + ch2 * 8 < NTOK)
                    v2 = *(const bf16x8*)&vt[vbase + (size_t)row2 * NTOK + kv0 + ch2 * 8];
                *(bf16x8*)&sVT[row2 * VP + ch2 * 8] = v2;
            }
        }
        __syncthreads();

        // S^T = K Q^T: sacc[rb][f] lane: q = rb*16+lr, keys = f*16 + 4g + j
        bf16x8 bk[4][2];
#pragma unroll
        for (int f = 0; f < 4; ++f)
#pragma unroll
            for (int ks = 0; ks < 2; ++ks)
                bk[f][ks] = *(const bf16x8*)&sK[(f * 16 + lr) * QP + ks * 32 + lk];
        f32x4 sacc[2][4] = {};
#pragma unroll
        for (int rb = 0; rb < 2; ++rb)
#pragma unroll
            for (int f = 0; f < 4; ++f) {
                sacc[rb][f] = __builtin_amdgcn_mfma_f32_16x16x32_bf16(bk[f][0], aq[rb][0], sacc[rb][f], 0, 0, 0);
                sacc[rb][f] = __builtin_amdgcn_mfma_f32_16x16x32_bf16(bk[f][1], aq[rb][1], sacc[rb][f], 0, 0, 0);
            }

        // p = 2^(s2-32); pack pairs (adjacent keys) -> b64 stores to sP[q][key]
#pragma unroll
        for (int rb = 0; rb < 2; ++rb)
#pragma unroll
            for (int f = 0; f < 4; ++f) {
                float p[4];
#pragma unroll
                for (int j = 0; j < 4; ++j) {
                    float arg = sacc[rb][f][j] - M2;
                    float pv;
                    asm("v_exp_f32 %0, %1" : "=v"(pv) : "v"(arg));
                    if (f >= 2 && tail) pv = 0.f;   // mask local keys >= 32
                    p[j] = pv;
                    l[rb] += pv;
                }
                uint u0, u1;
                asm("v_cvt_pk_bf16_f32 %0, %1, %2" : "=v"(u0) : "v"(p[0]), "v"(p[1]));
                asm("v_cvt_pk_bf16_f32 %0, %1, %2" : "=v"(u1) : "v"(p[2]), "v"(p[3]));
                uint2 uu; uu.x = u0; uu.y = u1;
                *(uint2*)&sP[w][(rb * 16 + lr) * PP + f * 16 + 4 * g] = uu;
            }

        // PV (swapped): o^T = mfma(V^T, P): lane: q = lr, d = 16nf + 4g + j
        bf16x8 bv[3][2];
#pragma unroll
        for (int nf = 0; nf < 3; ++nf)
#pragma unroll
            for (int ks = 0; ks < 2; ++ks)
                bv[nf][ks] = *(const bf16x8*)&sVT[(nf * 16 + lr) * VP + ks * 32 + lk];
#pragma unroll
        for (int rb = 0; rb < 2; ++rb) {
            bf16x8 pa0 = *(const bf16x8*)&sP[w][(rb * 16 + lr) * PP + lk];
            bf16x8 pa1 = *(const bf16x8*)&sP[w][(rb * 16 + lr) * PP + 32 + lk];
#pragma unroll
            for (int nf = 0; nf < 3; ++nf) {
                o[rb][nf] = __builtin_amdgcn_mfma_f32_16x16x32_bf16(bv[nf][0], pa0, o[rb][nf], 0, 0, 0);
                o[rb][nf] = __builtin_amdgcn_mfma_f32_16x16x32_bf16(bv[nf][1], pa1, o[rb][nf], 0, 0, 0);
            }
        }
    }

    // l reduction over g-lanes (lanes sharing lr have the same q)
#pragma unroll
    for (int rb = 0; rb < 2; ++rb) {
        l[rb] += __shfl_xor(l[rb], 16);
        l[rb] += __shfl_xor(l[rb], 32);
    }

    // epilogue: lane q = q0 + w*32 + rb*16 + lr; d = 16nf + 4g + j (contiguous)
#pragma unroll
    for (int rb = 0; rb < 2; ++rb) {
        int qr = q0 + w * 32 + rb * 16 + lr;
        if (qr < NTOK) {
            float inv = 1.f / l[rb];
            size_t rbse = ((size_t)b * NTOK + qr) * QKV_COLS;
#pragma unroll
            for (int nf = 0; nf < 3; ++nf) {
                ushort4 hi4, lo4;
#pragma unroll
                for (int j = 0; j < 4; ++j) {
                    float v = o[rb][nf][j] * inv;
                    ushort hv = f2b(v);
                    ((ushort*)&hi4)[j] = hv;
                    ((ushort*)&lo4)[j] = f2b(v - b2f(hv));
                }
                int c = h * HD + nf * 16 + 4 * g;
                *(ushort4*)&asplit[rbse + c] = hi4;
                *(ushort4*)&asplit[rbse + DIM + c] = lo4;
                *(ushort4*)&asplit[rbse + 2 * DIM + c] = hi4;
            }
        }
    }
}

// ---------------- launch ------------------------------------------------------
extern "C" void kernel_launch(void* const* d_in, const int* in_sizes, int n_in,
                              void* d_out, int out_size, void* d_ws, size_t ws_size,
                              hipStream_t stream) {
    const float* x   = (const float*)d_in[0];
    const int*   pos = (const int*)d_in[1];
    const float* Wq  = (const float*)d_in[2];
    const float* Wp  = (const float*)d_in[3];
    const float* bp  = (const float*)d_in[4];
    float* out = (float*)d_out;

    ushort* ws     = (ushort*)d_ws;
    ushort* x_bf   = ws;                                    // 6272*768 (later reused as vt)
    ushort* WqT    = x_bf + (size_t)ROWS * DIM;             // 2304*768
    ushort* WpT3   = WqT + (size_t)QKV_COLS * DIM;          // 768*2304
    ushort* qkv_bf = WpT3 + (size_t)DIM * QKV_COLS;         // 6272*2304
    ushort* asplit = qkv_bf + (size_t)ROWS * QKV_COLS;      // 6272*2304
    ushort* vt     = x_bf;   // alias: x_bf dead after gemm1; 4*768*1568 == 6272*768

    cast_f32_bf16<<<(ROWS * DIM / 4 + 255) / 256, 256, 0, stream>>>(x, x_bf, ROWS * DIM / 4);
    transpose_cast<<<dim3(QKV_COLS / 32, DIM / 32), dim3(32, 8), 0, stream>>>(Wq, WqT, DIM, QKV_COLS);
    split_transpose_wp<<<dim3(DIM / 32, DIM / 32), dim3(32, 8), 0, stream>>>(Wp, WpT3);

    // qkv = x @ W_qkv  (bf16 out)
    gemm_bf16<<<dim3(QKV_COLS / GBN, ROWS / GBM), 256, 0, stream>>>(
        x_bf, WqT, nullptr, qkv_bf, nullptr, ROWS, QKV_COLS, DIM);

    // vt[b][c][n] = V^T (overwrites x_bf, which is dead now)
    transpose_v<<<dim3(DIM / 32, NTOK / 32, BATCH), dim3(32, 8), 0, stream>>>(qkv_bf, vt);

    rope_bf16<<<(BATCH * NTOK * NHEADS * 3 * 8 + 255) / 256, 256, 0, stream>>>(qkv_bf, pos);

    attn_mfma<<<dim3((NTOK + QBLK - 1) / QBLK, BATCH * NHEADS), 256, 0, stream>>>(qkv_bf, vt, asplit);

    // out = asplit @ WpT3^T + b  (split-bf16, K=2304, f32 out)
    gemm_bf16<<<dim3(DIM / GBN, ROWS / GBM), 256, 0, stream>>>(
        asplit, WpT3, out, nullptr, bp, ROWS, DIM, QKV_COLS);
}

// Round 8
// 220.635 us; speedup vs baseline: 1.1114x; 1.1114x over previous
//
#include <hip/hip_runtime.h>
#include <hip/hip_bf16.h>
#include <math.h>

#define DIM 768
#define NHEADS 16
#define HD 48
#define NTOK 1568
#define BATCH 4
#define ROWS (BATCH * NTOK)     // 6272
#define QKV_COLS (3 * DIM)      // 2304

typedef __attribute__((ext_vector_type(8))) short bf16x8;
typedef __attribute__((ext_vector_type(4))) float f32x4;

__device__ inline float b2f(ushort u) {
    union { float f; unsigned u; } v; v.u = ((unsigned)u) << 16; return v.f;
}
__device__ inline ushort f2b(float f) {
    union { float f; unsigned u; } v; v.f = f;
    unsigned r = v.u + 0x7fff + ((v.u >> 16) & 1);   // round-to-nearest-even
    return (ushort)(r >> 16);
}

// ---------------- cast fp32 -> bf16 (vectorized) -----------------------------
__global__ void cast_f32_bf16(const float* __restrict__ in, ushort* __restrict__ out, int n4) {
    int i = blockIdx.x * blockDim.x + threadIdx.x;
    if (i >= n4) return;
    float4 v = ((const float4*)in)[i];
    ushort4 o;
    o.x = f2b(v.x); o.y = f2b(v.y); o.z = f2b(v.z); o.w = f2b(v.w);
    ((ushort4*)out)[i] = o;
}

// ---------------- transpose-cast: in[R][C] f32 -> out[C][R] bf16 -------------
__global__ void transpose_cast(const float* __restrict__ in, ushort* __restrict__ out,
                               int R, int C) {
    __shared__ ushort tile[32][33];
    int tx = threadIdx.x, ty = threadIdx.y;
    int c0 = blockIdx.x * 32, r0 = blockIdx.y * 32;
#pragma unroll
    for (int k = 0; k < 4; ++k)
        tile[ty + 8 * k][tx] = f2b(in[(size_t)(r0 + ty + 8 * k) * C + c0 + tx]);
    __syncthreads();
#pragma unroll
    for (int k = 0; k < 4; ++k)
        out[(size_t)(c0 + ty + 8 * k) * R + r0 + tx] = tile[tx][ty + 8 * k];
}

// ------- split-transpose W_proj [768][768] f32 -> out[768][2304] = [wh|wh|wl]
__global__ void split_transpose_wp(const float* __restrict__ in, ushort* __restrict__ out) {
    __shared__ float tile[32][33];
    int tx = threadIdx.x, ty = threadIdx.y;
    int c0 = blockIdx.x * 32, r0 = blockIdx.y * 32;   // r = k, c = n
#pragma unroll
    for (int k = 0; k < 4; ++k)
        tile[ty + 8 * k][tx] = in[(size_t)(r0 + ty + 8 * k) * DIM + c0 + tx];
    __syncthreads();
#pragma unroll
    for (int k = 0; k < 4; ++k) {
        float w = tile[tx][ty + 8 * k];
        ushort hi = f2b(w);
        ushort lo = f2b(w - b2f(hi));
        size_t base = (size_t)(c0 + ty + 8 * k) * QKV_COLS + r0 + tx;
        out[base] = hi; out[base + DIM] = hi; out[base + 2 * DIM] = lo;
    }
}

// ------- transpose V slice of qkv: vt[b][c][n] = qkv[b][n][1536+c], c in [0,768)
__global__ void transpose_v(const ushort* __restrict__ qkv, ushort* __restrict__ vt) {
    __shared__ ushort tile[32][33];
    int tx = threadIdx.x, ty = threadIdx.y;   // 32x8
    int c0 = blockIdx.x * 32, n0 = blockIdx.y * 32, b = blockIdx.z;
    const ushort* src = qkv + (size_t)b * NTOK * QKV_COLS + 2 * DIM;
#pragma unroll
    for (int k = 0; k < 4; ++k)
        tile[ty + 8 * k][tx] = src[(size_t)(n0 + ty + 8 * k) * QKV_COLS + c0 + tx];
    __syncthreads();
    ushort* dst = vt + (size_t)b * DIM * NTOK;
#pragma unroll
    for (int k = 0; k < 4; ++k)
        dst[(size_t)(c0 + ty + 8 * k) * NTOK + n0 + tx] = tile[tx][ty + 8 * k];
}

// ---------------- bf16 MFMA GEMM: C[M][N] = A[M][K] * Bt[N][K]^T -------------
#define GBM 128
#define GBN 128
#define GBK 64
#define LDP 72   // LDS pitch (bf16 elems)

__global__ __launch_bounds__(256) void gemm_bf16(
    const ushort* __restrict__ A, const ushort* __restrict__ Bt,
    float* __restrict__ Cf, ushort* __restrict__ Cb,
    const float* __restrict__ bias, int M, int N, int K) {
    __shared__ ushort sA[GBM * LDP];
    __shared__ ushort sB[GBN * LDP];
    const int tid = threadIdx.x;
    const int wid = tid >> 6, lane = tid & 63;
    const int wm = wid >> 1, wn = wid & 1;          // 2x2 wave grid, 64x64 per wave
    const int m0 = blockIdx.y * GBM, n0 = blockIdx.x * GBN;
    const int lr = lane & 15, lk = (lane >> 4) << 3;

    f32x4 acc[4][4] = {};
    for (int k0 = 0; k0 < K; k0 += GBK) {
        __syncthreads();
#pragma unroll
        for (int i = 0; i < 4; ++i) {
            int ci = tid + 256 * i;                  // 1024 chunks of 16B
            int row = ci >> 3, ch = ci & 7;
            *(bf16x8*)&sA[row * LDP + ch * 8] =
                *(const bf16x8*)&A[(size_t)(m0 + row) * K + k0 + ch * 8];
            *(bf16x8*)&sB[row * LDP + ch * 8] =
                *(const bf16x8*)&Bt[(size_t)(n0 + row) * K + k0 + ch * 8];
        }
        __syncthreads();
#pragma unroll
        for (int k2 = 0; k2 < GBK; k2 += 32) {
            bf16x8 af[4], bg[4];
#pragma unroll
            for (int f = 0; f < 4; ++f) {
                af[f] = *(const bf16x8*)&sA[(wm * 64 + f * 16 + lr) * LDP + k2 + lk];
                bg[f] = *(const bf16x8*)&sB[(wn * 64 + f * 16 + lr) * LDP + k2 + lk];
            }
#pragma unroll
            for (int mi = 0; mi < 4; ++mi)
#pragma unroll
                for (int ni = 0; ni < 4; ++ni)
                    acc[mi][ni] = __builtin_amdgcn_mfma_f32_16x16x32_bf16(
                        af[mi], bg[ni], acc[mi][ni], 0, 0, 0);
        }
    }
    const int cr = (lane >> 4) * 4;
#pragma unroll
    for (int mi = 0; mi < 4; ++mi)
#pragma unroll
        for (int ni = 0; ni < 4; ++ni) {
            int col = n0 + wn * 64 + ni * 16 + lr;
#pragma unroll
            for (int j = 0; j < 4; ++j) {
                int row = m0 + wm * 64 + mi * 16 + cr + j;
                float v = acc[mi][ni][j];
                if (Cf) {
                    if (bias) v += bias[col];
                    Cf[(size_t)row * N + col] = v;
                } else {
                    Cb[(size_t)row * N + col] = f2b(v);
                }
            }
        }
}

// ---------------- RoPE 3D in-place on bf16 qkv (q,k halves) ------------------
__global__ void rope_bf16(ushort* __restrict__ qkv, const int* __restrict__ pos) {
    int idx = blockIdx.x * blockDim.x + threadIdx.x;
    const int total = BATCH * NTOK * NHEADS * 3 * 8;   // 2408448
    if (idx >= total) return;
    int j = idx & 7; int t = idx >> 3;
    int axis = t % 3; t /= 3;
    int h = t & 15; t >>= 4;
    int n = t % NTOK; int b = t / NTOK;

    float p = (float)pos[n * 3 + axis];
    float freq = __powf(10000.0f, -(float)j * 0.125f);
    float ang = p * freq;
    float s, c; __sincosf(ang, &s, &c);

    size_t base = ((size_t)b * NTOK + n) * QKV_COLS + h * HD + axis * 16 + j;
    float q1 = b2f(qkv[base]), q2 = b2f(qkv[base + 8]);
    qkv[base]     = f2b(q1 * c - q2 * s);
    qkv[base + 8] = f2b(q2 * c + q1 * s);
    size_t kb = base + DIM;
    float k1 = b2f(qkv[kb]), k2 = b2f(qkv[kb + 8]);
    qkv[kb]     = f2b(k1 * c - k2 * s);
    qkv[kb + 8] = f2b(k2 * c + k1 * s);
}

// ---------------- MFMA flash attention (swapped-operand, fixed-offset SM) ----
// Grid: (13 q-tiles, 64 b*h). Block: 256 thr = 4 waves; wave owns 32 q-rows.
// Q loaded DIRECTLY to registers (no sQ -> LDS 18.7KB -> 8 blocks/CU).
// S^T = mfma(K,Q): lane q=lane&15, keys 4g+j contiguous -> cvt_pk + b64 P-store.
// PV swapped: o^T = mfma(V^T,P): lane q=lr, d=16nf+4g+j -> ushort4 C-stores.
// KVB=32 divides 1568 exactly: no tail anywhere.
#define QBLK 128
#define KVB 32
#define KP 72     // sK pitch (bf16)
#define VP 40     // sVT pitch
#define PP 40     // sP pitch

__global__ __launch_bounds__(256) void attn_mfma(const ushort* __restrict__ qkv,
                                                 const ushort* __restrict__ vt,
                                                 ushort* __restrict__ asplit) {
    __shared__ ushort sK[KVB * KP];        // 4.6 KB
    __shared__ ushort sVT[HD * VP];        // 3.8 KB
    __shared__ ushort sP[4][32 * PP];      // 10.2 KB
    const int tid = threadIdx.x, w = tid >> 6, lane = tid & 63;
    const int b = blockIdx.y >> 4, h = blockIdx.y & 15;
    const int q0 = blockIdx.x * QBLK;
    const size_t bbase = (size_t)b * NTOK * QKV_COLS;
    const size_t vbase = ((size_t)b * DIM + h * HD) * NTOK;
    const int lr = lane & 15, g = lane >> 4, lk = g << 3;
    // 1/sqrt(48) * log2(e): MFMA output lands directly in exp2 domain
    const float qs = 0.14433756729740643f * 1.4426950408889634f;
    const float M2 = 32.0f;   // fixed exp2-domain offset

    // Q direct to registers, scaled by qs. Lane needs rows w*32+rb*16+lr,
    // 16B chunks at cols {g*8, 32+g*8}; cols >= 48 are zero (nulls K garbage).
    bf16x8 aq[2][2];
#pragma unroll
    for (int rb = 0; rb < 2; ++rb) {
        int qr = q0 + w * 32 + rb * 16 + lr;
        if (qr >= NTOK) qr = NTOK - 1;
        const ushort* qp = &qkv[bbase + (size_t)qr * QKV_COLS + h * HD];
        bf16x8 r0 = *(const bf16x8*)&qp[lk];
        bf16x8 r1 = {};
        if (g < 2) r1 = *(const bf16x8*)&qp[32 + lk];
#pragma unroll
        for (int e = 0; e < 8; ++e) {
            r0[e] = (short)f2b(b2f((ushort)r0[e]) * qs);
            r1[e] = (short)f2b(b2f((ushort)r1[e]) * qs);
        }
        aq[rb][0] = r0; aq[rb][1] = r1;
    }

    float l[2] = {0.f, 0.f};
    f32x4 o[2][3] = {};

    for (int kv0 = 0; kv0 < NTOK; kv0 += KVB) {
        __syncthreads();
        {   // stage K: 32 rows x 8 chunks = 256 b128 writes (cols 48..63 garbage ok)
            int row = tid >> 3, ch = tid & 7;
            *(bf16x8*)&sK[row * KP + ch * 8] =
                *(const bf16x8*)&qkv[bbase + (size_t)(kv0 + row) * QKV_COLS + DIM + h * HD + ch * 8];
        }
        if (tid < 192) {   // stage V^T: 48 d-rows x 4 chunks, vectorized
            int d = tid >> 2, c = tid & 3;
            *(bf16x8*)&sVT[d * VP + c * 8] =
                *(const bf16x8*)&vt[vbase + (size_t)d * NTOK + kv0 + c * 8];
        }
        __syncthreads();

        // S^T = K Q^T: sacc[rb][f] lane: q = rb*16+lr, keys = f*16 + 4g + j
        bf16x8 bk[2][2];
#pragma unroll
        for (int f = 0; f < 2; ++f)
#pragma unroll
            for (int ks = 0; ks < 2; ++ks)
                bk[f][ks] = *(const bf16x8*)&sK[(f * 16 + lr) * KP + ks * 32 + lk];
        f32x4 sacc[2][2] = {};
#pragma unroll
        for (int rb = 0; rb < 2; ++rb)
#pragma unroll
            for (int f = 0; f < 2; ++f) {
                sacc[rb][f] = __builtin_amdgcn_mfma_f32_16x16x32_bf16(bk[f][0], aq[rb][0], sacc[rb][f], 0, 0, 0);
                sacc[rb][f] = __builtin_amdgcn_mfma_f32_16x16x32_bf16(bk[f][1], aq[rb][1], sacc[rb][f], 0, 0, 0);
            }

        // p = 2^(s2-32); pack adjacent-key pairs -> b64 stores to sP[q][key]
#pragma unroll
        for (int rb = 0; rb < 2; ++rb)
#pragma unroll
            for (int f = 0; f < 2; ++f) {
                float p[4];
#pragma unroll
                for (int j = 0; j < 4; ++j) {
                    float arg = sacc[rb][f][j] - M2;
                    float pv;
                    asm("v_exp_f32 %0, %1" : "=v"(pv) : "v"(arg));
                    p[j] = pv;
                    l[rb] += pv;
                }
                uint u0, u1;
                asm("v_cvt_pk_bf16_f32 %0, %1, %2" : "=v"(u0) : "v"(p[0]), "v"(p[1]));
                asm("v_cvt_pk_bf16_f32 %0, %1, %2" : "=v"(u1) : "v"(p[2]), "v"(p[3]));
                uint2 uu; uu.x = u0; uu.y = u1;
                *(uint2*)&sP[w][(rb * 16 + lr) * PP + f * 16 + 4 * g] = uu;
            }

        // PV (swapped): o^T = mfma(V^T, P): lane: q = lr, d = 16nf + 4g + j
        bf16x8 bv[3];
#pragma unroll
        for (int nf = 0; nf < 3; ++nf)
            bv[nf] = *(const bf16x8*)&sVT[(nf * 16 + lr) * VP + lk];
#pragma unroll
        for (int rb = 0; rb < 2; ++rb) {
            bf16x8 pa = *(const bf16x8*)&sP[w][(rb * 16 + lr) * PP + lk];
#pragma unroll
            for (int nf = 0; nf < 3; ++nf)
                o[rb][nf] = __builtin_amdgcn_mfma_f32_16x16x32_bf16(bv[nf], pa, o[rb][nf], 0, 0, 0);
        }
    }

    // l reduction over g-lanes (lanes sharing lr have the same q)
#pragma unroll
    for (int rb = 0; rb < 2; ++rb) {
        l[rb] += __shfl_xor(l[rb], 16);
        l[rb] += __shfl_xor(l[rb], 32);
    }

    // epilogue: lane q = q0 + w*32 + rb*16 + lr; d = 16nf + 4g + j (contiguous)
#pragma unroll
    for (int rb = 0; rb < 2; ++rb) {
        int qr = q0 + w * 32 + rb * 16 + lr;
        if (qr < NTOK) {
            float inv = 1.f / l[rb];
            size_t rbse = ((size_t)b * NTOK + qr) * QKV_COLS;
#pragma unroll
            for (int nf = 0; nf < 3; ++nf) {
                ushort4 hi4, lo4;
#pragma unroll
                for (int j = 0; j < 4; ++j) {
                    float v = o[rb][nf][j] * inv;
                    ushort hv = f2b(v);
                    ((ushort*)&hi4)[j] = hv;
                    ((ushort*)&lo4)[j] = f2b(v - b2f(hv));
                }
                int c = h * HD + nf * 16 + 4 * g;
                *(ushort4*)&asplit[rbse + c] = hi4;
                *(ushort4*)&asplit[rbse + DIM + c] = lo4;
                *(ushort4*)&asplit[rbse + 2 * DIM + c] = hi4;
            }
        }
    }
}

// ---------------- launch ------------------------------------------------------
extern "C" void kernel_launch(void* const* d_in, const int* in_sizes, int n_in,
                              void* d_out, int out_size, void* d_ws, size_t ws_size,
                              hipStream_t stream) {
    const float* x   = (const float*)d_in[0];
    const int*   pos = (const int*)d_in[1];
    const float* Wq  = (const float*)d_in[2];
    const float* Wp  = (const float*)d_in[3];
    const float* bp  = (const float*)d_in[4];
    float* out = (float*)d_out;

    ushort* ws     = (ushort*)d_ws;
    ushort* x_bf   = ws;                                    // 6272*768 (later reused as vt)
    ushort* WqT    = x_bf + (size_t)ROWS * DIM;             // 2304*768
    ushort* WpT3   = WqT + (size_t)QKV_COLS * DIM;          // 768*2304
    ushort* qkv_bf = WpT3 + (size_t)DIM * QKV_COLS;         // 6272*2304
    ushort* asplit = qkv_bf + (size_t)ROWS * QKV_COLS;      // 6272*2304
    ushort* vt     = x_bf;   // alias: x_bf dead after gemm1; 4*768*1568 == 6272*768

    cast_f32_bf16<<<(ROWS * DIM / 4 + 255) / 256, 256, 0, stream>>>(x, x_bf, ROWS * DIM / 4);
    transpose_cast<<<dim3(QKV_COLS / 32, DIM / 32), dim3(32, 8), 0, stream>>>(Wq, WqT, DIM, QKV_COLS);
    split_transpose_wp<<<dim3(DIM / 32, DIM / 32), dim3(32, 8), 0, stream>>>(Wp, WpT3);

    // qkv = x @ W_qkv  (bf16 out)
    gemm_bf16<<<dim3(QKV_COLS / GBN, ROWS / GBM), 256, 0, stream>>>(
        x_bf, WqT, nullptr, qkv_bf, nullptr, ROWS, QKV_COLS, DIM);

    // vt[b][c][n] = V^T (overwrites x_bf, which is dead now)
    transpose_v<<<dim3(DIM / 32, NTOK / 32, BATCH), dim3(32, 8), 0, stream>>>(qkv_bf, vt);

    rope_bf16<<<(BATCH * NTOK * NHEADS * 3 * 8 + 255) / 256, 256, 0, stream>>>(qkv_bf, pos);

    attn_mfma<<<dim3((NTOK + QBLK - 1) / QBLK, BATCH * NHEADS), 256, 0, stream>>>(qkv_bf, vt, asplit);

    // out = asplit @ WpT3^T + b  (split-bf16, K=2304, f32 out)
    gemm_bf16<<<dim3(DIM / GBN, ROWS / GBM), 256, 0, stream>>>(
        asplit, WpT3, out, nullptr, bp, ROWS, DIM, QKV_COLS);
}

// Round 9
// 213.371 us; speedup vs baseline: 1.1493x; 1.0340x over previous
//
#include <hip/hip_runtime.h>
#include <hip/hip_bf16.h>
#include <math.h>

#define DIM 768
#define NHEADS 16
#define HD 48
#define NTOK 1568
#define BATCH 4
#define ROWS (BATCH * NTOK)     // 6272
#define QKV_COLS (3 * DIM)      // 2304

typedef __attribute__((ext_vector_type(8))) short bf16x8;
typedef __attribute__((ext_vector_type(4))) float f32x4;

__device__ inline float b2f(ushort u) {
    union { float f; unsigned u; } v; v.u = ((unsigned)u) << 16; return v.f;
}
__device__ inline ushort f2b(float f) {
    union { float f; unsigned u; } v; v.f = f;
    unsigned r = v.u + 0x7fff + ((v.u >> 16) & 1);   // round-to-nearest-even
    return (ushort)(r >> 16);
}

// async global->LDS, 16B per lane; lds dest must be wave-uniform base (+lane*16 by HW)
__device__ inline void gl16(const void* g, void* l) {
    __builtin_amdgcn_global_load_lds(
        (const __attribute__((address_space(1))) unsigned int*)g,
        (__attribute__((address_space(3))) unsigned int*)l, 16, 0, 0);
}

// ---------------- cast fp32 -> bf16 (vectorized) -----------------------------
__global__ void cast_f32_bf16(const float* __restrict__ in, ushort* __restrict__ out, int n4) {
    int i = blockIdx.x * blockDim.x + threadIdx.x;
    if (i >= n4) return;
    float4 v = ((const float4*)in)[i];
    ushort4 o;
    o.x = f2b(v.x); o.y = f2b(v.y); o.z = f2b(v.z); o.w = f2b(v.w);
    ((ushort4*)out)[i] = o;
}

// ---------------- transpose-cast: in[R][C] f32 -> out[C][R] bf16 -------------
__global__ void transpose_cast(const float* __restrict__ in, ushort* __restrict__ out,
                               int R, int C) {
    __shared__ ushort tile[32][33];
    int tx = threadIdx.x, ty = threadIdx.y;
    int c0 = blockIdx.x * 32, r0 = blockIdx.y * 32;
#pragma unroll
    for (int k = 0; k < 4; ++k)
        tile[ty + 8 * k][tx] = f2b(in[(size_t)(r0 + ty + 8 * k) * C + c0 + tx]);
    __syncthreads();
#pragma unroll
    for (int k = 0; k < 4; ++k)
        out[(size_t)(c0 + ty + 8 * k) * R + r0 + tx] = tile[tx][ty + 8 * k];
}

// ------- split-transpose W_proj [768][768] f32 -> out[768][2304] = [wh|wh|wl]
__global__ void split_transpose_wp(const float* __restrict__ in, ushort* __restrict__ out) {
    __shared__ float tile[32][33];
    int tx = threadIdx.x, ty = threadIdx.y;
    int c0 = blockIdx.x * 32, r0 = blockIdx.y * 32;   // r = k, c = n
#pragma unroll
    for (int k = 0; k < 4; ++k)
        tile[ty + 8 * k][tx] = in[(size_t)(r0 + ty + 8 * k) * DIM + c0 + tx];
    __syncthreads();
#pragma unroll
    for (int k = 0; k < 4; ++k) {
        float w = tile[tx][ty + 8 * k];
        ushort hi = f2b(w);
        ushort lo = f2b(w - b2f(hi));
        size_t base = (size_t)(c0 + ty + 8 * k) * QKV_COLS + r0 + tx;
        out[base] = hi; out[base + DIM] = hi; out[base + 2 * DIM] = lo;
    }
}

// ------- transpose V slice of qkv: vt[b][c][n] = qkv[b][n][1536+c], c in [0,768)
__global__ void transpose_v(const ushort* __restrict__ qkv, ushort* __restrict__ vt) {
    __shared__ ushort tile[32][33];
    int tx = threadIdx.x, ty = threadIdx.y;   // 32x8
    int c0 = blockIdx.x * 32, n0 = blockIdx.y * 32, b = blockIdx.z;
    const ushort* src = qkv + (size_t)b * NTOK * QKV_COLS + 2 * DIM;
#pragma unroll
    for (int k = 0; k < 4; ++k)
        tile[ty + 8 * k][tx] = src[(size_t)(n0 + ty + 8 * k) * QKV_COLS + c0 + tx];
    __syncthreads();
    ushort* dst = vt + (size_t)b * DIM * NTOK;
#pragma unroll
    for (int k = 0; k < 4; ++k)
        dst[(size_t)(c0 + ty + 8 * k) * NTOK + n0 + tx] = tile[tx][ty + 8 * k];
}

// ---------------- bf16 MFMA GEMM: C[M][N] = A[M][K] * Bt[N][K]^T -------------
// global_load_lds staging, linear LDS [row][64] with both-sides XOR swizzle:
// source chunk ch = ch' ^ (row&7); read byte ^= (row&7)<<4.
#define GBM 128
#define GBN 128
#define GBK 64

__global__ __launch_bounds__(256) void gemm_bf16(
    const ushort* __restrict__ A, const ushort* __restrict__ Bt,
    float* __restrict__ Cf, ushort* __restrict__ Cb,
    const float* __restrict__ bias, int M, int N, int K) {
    __shared__ ushort sA[GBM * 64];
    __shared__ ushort sB[GBN * 64];
    const int tid = threadIdx.x;
    const int wid = tid >> 6, lane = tid & 63;
    const int wm = wid >> 1, wn = wid & 1;          // 2x2 wave grid, 64x64 per wave
    const int m0 = blockIdx.y * GBM, n0 = blockIdx.x * GBN;
    const int lr = lane & 15, g = lane >> 4;

    f32x4 acc[4][4] = {};
    for (int k0 = 0; k0 < K; k0 += GBK) {
        __syncthreads();
#pragma unroll
        for (int i = 0; i < 4; ++i) {
            int c = tid + 256 * i;                   // 1024 chunks of 16B
            int row = c >> 3;
            int ch = (c & 7) ^ (row & 7);            // source pre-swizzle
            int ub = (c & ~63) * 8;                  // wave-uniform dest (ushort idx)
            gl16(&A[(size_t)(m0 + row) * K + k0 + ch * 8], &sA[ub]);
            gl16(&Bt[(size_t)(n0 + row) * K + k0 + ch * 8], &sB[ub]);
        }
        __syncthreads();                             // drains vmcnt: tiles ready
#pragma unroll
        for (int k2 = 0; k2 < GBK; k2 += 32) {
            bf16x8 af[4], bg[4];
#pragma unroll
            for (int f = 0; f < 4; ++f) {
                int ra = wm * 64 + f * 16 + lr;
                int ba = (ra * 128 + k2 * 2 + g * 16) ^ ((ra & 7) << 4);
                af[f] = *(const bf16x8*)((const char*)sA + ba);
                int rb = wn * 64 + f * 16 + lr;
                int bb = (rb * 128 + k2 * 2 + g * 16) ^ ((rb & 7) << 4);
                bg[f] = *(const bf16x8*)((const char*)sB + bb);
            }
#pragma unroll
            for (int mi = 0; mi < 4; ++mi)
#pragma unroll
                for (int ni = 0; ni < 4; ++ni)
                    acc[mi][ni] = __builtin_amdgcn_mfma_f32_16x16x32_bf16(
                        af[mi], bg[ni], acc[mi][ni], 0, 0, 0);
        }
    }
    const int cr = (lane >> 4) * 4;
#pragma unroll
    for (int mi = 0; mi < 4; ++mi)
#pragma unroll
        for (int ni = 0; ni < 4; ++ni) {
            int col = n0 + wn * 64 + ni * 16 + lr;
#pragma unroll
            for (int j = 0; j < 4; ++j) {
                int row = m0 + wm * 64 + mi * 16 + cr + j;
                float v = acc[mi][ni][j];
                if (Cf) {
                    if (bias) v += bias[col];
                    Cf[(size_t)row * N + col] = v;
                } else {
                    Cb[(size_t)row * N + col] = f2b(v);
                }
            }
        }
}

// ---------------- RoPE 3D in-place on bf16 qkv (q,k halves) ------------------
__global__ void rope_bf16(ushort* __restrict__ qkv, const int* __restrict__ pos) {
    int idx = blockIdx.x * blockDim.x + threadIdx.x;
    const int total = BATCH * NTOK * NHEADS * 3 * 8;   // 2408448
    if (idx >= total) return;
    int j = idx & 7; int t = idx >> 3;
    int axis = t % 3; t /= 3;
    int h = t & 15; t >>= 4;
    int n = t % NTOK; int b = t / NTOK;

    float p = (float)pos[n * 3 + axis];
    float freq = __powf(10000.0f, -(float)j * 0.125f);
    float ang = p * freq;
    float s, c; __sincosf(ang, &s, &c);

    size_t base = ((size_t)b * NTOK + n) * QKV_COLS + h * HD + axis * 16 + j;
    float q1 = b2f(qkv[base]), q2 = b2f(qkv[base + 8]);
    qkv[base]     = f2b(q1 * c - q2 * s);
    qkv[base + 8] = f2b(q2 * c + q1 * s);
    size_t kb = base + DIM;
    float k1 = b2f(qkv[kb]), k2 = b2f(qkv[kb + 8]);
    qkv[kb]     = f2b(k1 * c - k2 * s);
    qkv[kb + 8] = f2b(k2 * c + k1 * s);
}

// ---------------- MFMA flash attention ---------------------------------------
// Grid: (64 bh, 13 q-tiles) — same-bh blocks share id%8 -> same XCD L2 for K/V.
// Double-buffered K/V staged via global_load_lds (counted vmcnt(2), raw
// barriers): tile t+1 loads fly under tile t compute. Both-sides XOR swizzle.
// Q direct to regs. Fixed-offset exp2 softmax (no max tracking). KVB=32 | 1568.
#define QBLK 128
#define KVB 32
#define NT (NTOK / KVB)   // 49
#define PP 40             // sP pitch

__global__ __launch_bounds__(256) void attn_mfma(const ushort* __restrict__ qkv,
                                                 const ushort* __restrict__ vt,
                                                 ushort* __restrict__ asplit) {
    __shared__ ushort sK2[2][KVB * 64];   // [32][64] linear, 16 KB
    __shared__ ushort sV2[2][HD * 32];    // [48][32] linear, 6 KB
    __shared__ ushort sP[4][32 * PP];     // 10 KB
    const int tid = threadIdx.x, w = tid >> 6, lane = tid & 63;
    const int b = blockIdx.x >> 4, h = blockIdx.x & 15;
    const int q0 = blockIdx.y * QBLK;
    const size_t bbase = (size_t)b * NTOK * QKV_COLS;
    const size_t vbase = ((size_t)b * DIM + h * HD) * NTOK;
    const int lr = lane & 15, g = lane >> 4, lk = g << 3;
    const float qs = 0.14433756729740643f * 1.4426950408889634f;  // 1/sqrt(48)*log2e
    const float M2 = 32.0f;   // fixed exp2-domain offset

    // Q direct to registers, scaled by qs; cols >= 48 zero (nulls K garbage)
    bf16x8 aq[2][2];
#pragma unroll
    for (int rb = 0; rb < 2; ++rb) {
        int qr = q0 + w * 32 + rb * 16 + lr;
        if (qr >= NTOK) qr = NTOK - 1;
        const ushort* qp = &qkv[bbase + (size_t)qr * QKV_COLS + h * HD];
        bf16x8 r0 = *(const bf16x8*)&qp[lk];
        bf16x8 r1 = {};
        if (g < 2) r1 = *(const bf16x8*)&qp[32 + lk];
#pragma unroll
        for (int e = 0; e < 8; ++e) {
            r0[e] = (short)f2b(b2f((ushort)r0[e]) * qs);
            r1[e] = (short)f2b(b2f((ushort)r1[e]) * qs);
        }
        aq[rb][0] = r0; aq[rb][1] = r1;
    }

    // stage K (256 chunks) + V (192 chunks) for tile kv0 into buffer buf
    auto STAGE = [&](int buf, int kv0) {
        {   // K: chunk c = tid; row = c>>3; source chunk swizzled
            int c = tid, row = c >> 3;
            int ch = (c & 7) ^ (row & 7);
            gl16(&qkv[bbase + (size_t)(kv0 + row) * QKV_COLS + DIM + h * HD + ch * 8],
                 &sK2[buf][(c & ~63) * 8]);
        }
        if (lane < 48) {   // V: wave w stages chunks w*48..w*48+47
            int c = w * 48 + lane, d = c >> 2;
            int cc = (c & 3) ^ ((d >> 1) & 3);
            gl16(&vt[vbase + (size_t)d * NTOK + kv0 + cc * 8],
                 &sV2[buf][w * 384]);
        }
    };

    float l[2] = {0.f, 0.f};
    f32x4 o[2][3] = {};

    STAGE(0, 0);
    for (int t = 0; t < NT; ++t) {
        const int cur = t & 1;
        if (t + 1 < NT) {
            STAGE(cur ^ 1, (t + 1) * KVB);
            asm volatile("s_waitcnt vmcnt(2)" ::: "memory");  // tile t's 2 loads done
        } else {
            asm volatile("s_waitcnt vmcnt(0)" ::: "memory");
        }
        __builtin_amdgcn_s_barrier();

        // S^T = K Q^T: sacc[rb][f] lane: q = rb*16+lr, keys = f*16 + 4g + j
        bf16x8 bk[2][2];
#pragma unroll
        for (int f = 0; f < 2; ++f)
#pragma unroll
            for (int ks = 0; ks < 2; ++ks) {
                int row = f * 16 + lr;
                int byt = (row * 128 + ks * 64 + g * 16) ^ ((lr & 7) << 4);
                bk[f][ks] = *(const bf16x8*)((const char*)sK2[cur] + byt);
            }
        f32x4 sacc[2][2] = {};
#pragma unroll
        for (int rb = 0; rb < 2; ++rb)
#pragma unroll
            for (int f = 0; f < 2; ++f) {
                sacc[rb][f] = __builtin_amdgcn_mfma_f32_16x16x32_bf16(bk[f][0], aq[rb][0], sacc[rb][f], 0, 0, 0);
                sacc[rb][f] = __builtin_amdgcn_mfma_f32_16x16x32_bf16(bk[f][1], aq[rb][1], sacc[rb][f], 0, 0, 0);
            }

        // p = 2^(s2-32); pack adjacent-key pairs -> b64 stores to sP[q][key]
#pragma unroll
        for (int rb = 0; rb < 2; ++rb)
#pragma unroll
            for (int f = 0; f < 2; ++f) {
                float p[4];
#pragma unroll
                for (int j = 0; j < 4; ++j) {
                    float arg = sacc[rb][f][j] - M2;
                    float pv;
                    asm("v_exp_f32 %0, %1" : "=v"(pv) : "v"(arg));
                    p[j] = pv;
                    l[rb] += pv;
                }
                uint u0, u1;
                asm("v_cvt_pk_bf16_f32 %0, %1, %2" : "=v"(u0) : "v"(p[0]), "v"(p[1]));
                asm("v_cvt_pk_bf16_f32 %0, %1, %2" : "=v"(u1) : "v"(p[2]), "v"(p[3]));
                uint2 uu; uu.x = u0; uu.y = u1;
                *(uint2*)&sP[w][(rb * 16 + lr) * PP + f * 16 + 4 * g] = uu;
            }

        // PV (swapped): o^T = mfma(V^T, P): lane: q = lr, d = 16nf + 4g + j
        bf16x8 bv[3];
#pragma unroll
        for (int nf = 0; nf < 3; ++nf) {
            int row = nf * 16 + lr;
            int byt = (row * 64 + g * 16) ^ (((lr >> 1) & 3) << 4);
            bv[nf] = *(const bf16x8*)((const char*)sV2[cur] + byt);
        }
#pragma unroll
        for (int rb = 0; rb < 2; ++rb) {
            bf16x8 pa = *(const bf16x8*)&sP[w][(rb * 16 + lr) * PP + lk];
#pragma unroll
            for (int nf = 0; nf < 3; ++nf)
                o[rb][nf] = __builtin_amdgcn_mfma_f32_16x16x32_bf16(bv[nf], pa, o[rb][nf], 0, 0, 0);
        }

        asm volatile("s_waitcnt lgkmcnt(0)" ::: "memory");  // LDS ops retired
        __builtin_amdgcn_s_barrier();                       // buffer-reuse fence
    }

    // l reduction over g-lanes (lanes sharing lr have the same q)
#pragma unroll
    for (int rb = 0; rb < 2; ++rb) {
        l[rb] += __shfl_xor(l[rb], 16);
        l[rb] += __shfl_xor(l[rb], 32);
    }

    // epilogue: lane q = q0 + w*32 + rb*16 + lr; d = 16nf + 4g + j (contiguous)
#pragma unroll
    for (int rb = 0; rb < 2; ++rb) {
        int qr = q0 + w * 32 + rb * 16 + lr;
        if (qr < NTOK) {
            float inv = 1.f / l[rb];
            size_t rbse = ((size_t)b * NTOK + qr) * QKV_COLS;
#pragma unroll
            for (int nf = 0; nf < 3; ++nf) {
                ushort4 hi4, lo4;
#pragma unroll
                for (int j = 0; j < 4; ++j) {
                    float v = o[rb][nf][j] * inv;
                    ushort hv = f2b(v);
                    ((ushort*)&hi4)[j] = hv;
                    ((ushort*)&lo4)[j] = f2b(v - b2f(hv));
                }
                int c = h * HD + nf * 16 + 4 * g;
                *(ushort4*)&asplit[rbse + c] = hi4;
                *(ushort4*)&asplit[rbse + DIM + c] = lo4;
                *(ushort4*)&asplit[rbse + 2 * DIM + c] = hi4;
            }
        }
    }
}

// ---------------- launch ------------------------------------------------------
extern "C" void kernel_launch(void* const* d_in, const int* in_sizes, int n_in,
                              void* d_out, int out_size, void* d_ws, size_t ws_size,
                              hipStream_t stream) {
    const float* x   = (const float*)d_in[0];
    const int*   pos = (const int*)d_in[1];
    const float* Wq  = (const float*)d_in[2];
    const float* Wp  = (const float*)d_in[3];
    const float* bp  = (const float*)d_in[4];
    float* out = (float*)d_out;

    ushort* ws     = (ushort*)d_ws;
    ushort* x_bf   = ws;                                    // 6272*768 (later reused as vt)
    ushort* WqT    = x_bf + (size_t)ROWS * DIM;             // 2304*768
    ushort* WpT3   = WqT + (size_t)QKV_COLS * DIM;          // 768*2304
    ushort* qkv_bf = WpT3 + (size_t)DIM * QKV_COLS;         // 6272*2304
    ushort* asplit = qkv_bf + (size_t)ROWS * QKV_COLS;      // 6272*2304
    ushort* vt     = x_bf;   // alias: x_bf dead after gemm1; 4*768*1568 == 6272*768

    cast_f32_bf16<<<(ROWS * DIM / 4 + 255) / 256, 256, 0, stream>>>(x, x_bf, ROWS * DIM / 4);
    transpose_cast<<<dim3(QKV_COLS / 32, DIM / 32), dim3(32, 8), 0, stream>>>(Wq, WqT, DIM, QKV_COLS);
    split_transpose_wp<<<dim3(DIM / 32, DIM / 32), dim3(32, 8), 0, stream>>>(Wp, WpT3);

    // qkv = x @ W_qkv  (bf16 out)
    gemm_bf16<<<dim3(QKV_COLS / GBN, ROWS / GBM), 256, 0, stream>>>(
        x_bf, WqT, nullptr, qkv_bf, nullptr, ROWS, QKV_COLS, DIM);

    // vt[b][c][n] = V^T (overwrites x_bf, which is dead now)
    transpose_v<<<dim3(DIM / 32, NTOK / 32, BATCH), dim3(32, 8), 0, stream>>>(qkv_bf, vt);

    rope_bf16<<<(BATCH * NTOK * NHEADS * 3 * 8 + 255) / 256, 256, 0, stream>>>(qkv_bf, pos);

    attn_mfma<<<dim3(BATCH * NHEADS, (NTOK + QBLK - 1) / QBLK), 256, 0, stream>>>(qkv_bf, vt, asplit);

    // out = asplit @ WpT3^T + b  (split-bf16, K=2304, f32 out)
    gemm_bf16<<<dim3(DIM / GBN, ROWS / GBM), 256, 0, stream>>>(
        asplit, WpT3, out, nullptr, bp, ROWS, DIM, QKV_COLS);
}